// Round 8
// baseline (586.603 us; speedup 1.0000x reference)
//
#include <hip/hip_runtime.h>
#include <hip/hip_bf16.h>
#include <math.h>
#include <string.h>

#define HID 32
#define PSHIFT 8                 // dst bucket = dst >> 8 (256 nodes/bucket)
#define NPB (1 << PSHIFT)
#define MAXP 512                 // partition scan width (supports N <= 131072)
#define SLOTS 17408              // per-bucket staging; mean 16384, +8 sigma (guarded)
#define SBITS 3                  // src octile bits: bin = src >> 14
#define SBINS (1 << SBITS)
#define NBINS (NPB * SBINS)      // 2048 counting-sort bins
#define GS 32                    // gcur stride in ints: 1 counter per 128B cacheline
#define HS_ROWS 32               // hsum partial rows (spread atomic contention)
#define COLBUF 3072              // mlp_fused col slice; 32 nodes, mean 2048 (guarded)
#define COLBUF0 6144             // mlp0 col slice; 64 nodes, mean 4096 (guarded)
#define EPB 16384                // partition: edges per block (4 chunks of 4096)
typedef unsigned short u16;
typedef unsigned char u8;

// ---------- fp8 e4m3 helpers (non-negative activations; ftz-tolerant) ----------
__device__ inline float e42f(unsigned b) {
    unsigned u = (b & 0x7fu) << 20;
    float f; memcpy(&f, &u, 4);
    return f * 0x1p120f;
}
__device__ inline unsigned f2e4(float f) {
    f = fminf(f, 448.f);
    float y = f * 0x1p-120f;
    unsigned r; memcpy(&r, &y, 4);
    r = r + 0x7FFFFu + ((r >> 20) & 1u);
    return (r >> 20) & 0x7fu;
}
__device__ inline void acc_e4(float* a, unsigned w) {
    a[0] += e42f(w);
    a[1] += e42f(w >> 8);
    a[2] += e42f(w >> 16);
    a[3] += e42f(w >> 24);
}

// ---------------- zero / init ----------------
__global__ void zero_kernel(float* __restrict__ p, int n) {
    int i = blockIdx.x * blockDim.x + threadIdx.x;
    if (i < n) p[i] = 0.f;
}
__global__ void init_gcur(int* __restrict__ gcur, int P) {
    int b = blockIdx.x * blockDim.x + threadIdx.x;
    if (b < P) gcur[b * GS] = b * SLOTS;
}

// ---------------- phase 1: partition, 16K edges/block, 4 chunks ----------------
// R7 counters: VALUBusy 8%, HBM 18%, occ 31% -> block latency ~88K cycles, dominated by
// per-bucket gcur atomic-with-return: 1563 RMWs per bucket-line serialized at LLC.
// This version: one reservation per bucket per 16K-edge block -> 391 RMWs/line (4x less),
// grid = 391 blocks (all resident, no tail), write runs 42B -> 168B (less write amp).
__global__ void partition_edges(const int* __restrict__ src, const int* __restrict__ dst,
                                int* __restrict__ gcur, unsigned* __restrict__ staged,
                                int E, int P) {
    __shared__ int hc[4][MAXP];         // 8 KB per-CHUNK hist (wave w hists chunk w)
    __shared__ int hbase[MAXP];         // 2 KB chunk-local exclusive scan
    __shared__ int cur[MAXP];           // 2 KB placement cursors
    __shared__ int run[MAXP];           // 2 KB global running write cursor per bucket
    __shared__ unsigned sortedv[4096];  // 16 KB packed edges, bucket-major (per chunk)
    __shared__ u16 bktid[4096];         // 8 KB bucket id per slot
    __shared__ int wsums[4];
    __shared__ int sTotal;
    int t = threadIdx.x, wid = t >> 6, lane = t & 63;
    for (int i = t; i < 4 * MAXP; i += 256) (&hc[0][0])[i] = 0;
    __syncthreads();

    int base = blockIdx.x * EPB;

    // ---- phase 1: wave w histograms chunk w (dst only; coalesced 16B/lane) ----
    {
        int cbase = base + wid * 4096;
#pragma unroll
        for (int k = 0; k < 16; k++) {
            int e = cbase + k * 256 + lane * 4;
            int4 D;
            if (e + 3 < E) {
                D = *(const int4*)(dst + e);
            } else {
                int d0[4];
                for (int j = 0; j < 4; j++) d0[j] = (e + j < E) ? dst[e + j] : -1;
                D = make_int4(d0[0], d0[1], d0[2], d0[3]);
            }
            if (D.x >= 0) atomicAdd(&hc[wid][D.x >> PSHIFT], 1);
            if (D.y >= 0) atomicAdd(&hc[wid][D.y >> PSHIFT], 1);
            if (D.z >= 0) atomicAdd(&hc[wid][D.z >> PSHIFT], 1);
            if (D.w >= 0) atomicAdd(&hc[wid][D.w >> PSHIFT], 1);
        }
    }
    __syncthreads();

    // ---- reservation: ONE global atomic per bucket for all 16K edges ----
    int b0 = 2 * t, b1 = 2 * t + 1;
    int tot0 = 0, tot1 = 0;
    if (b0 < P) tot0 = hc[0][b0] + hc[1][b0] + hc[2][b0] + hc[3][b0];
    if (b1 < P) tot1 = hc[0][b1] + hc[1][b1] + hc[2][b1] + hc[3][b1];
    if (b0 < P && tot0) run[b0] = atomicAdd(&gcur[b0 * GS], tot0);
    if (b1 < P && tot1) run[b1] = atomicAdd(&gcur[b1 * GS], tot1);

    // ---- phase 2: per chunk: scan(hc[c]) -> place -> writeout -> advance run ----
    for (int c = 0; c < 4; c++) {
        int t0 = (b0 < P) ? hc[c][b0] : 0;
        int t1 = (b1 < P) ? hc[c][b1] : 0;
        int s = t0 + t1;
        int incl = s;
#pragma unroll
        for (int off = 1; off < 64; off <<= 1) {
            int u = __shfl_up(incl, off, 64);
            if (lane >= off) incl += u;
        }
        if (lane == 63) wsums[wid] = incl;
        __syncthreads();
        int woff = 0;
#pragma unroll
        for (int w = 0; w < 4; w++) if (w < wid) woff += wsums[w];
        int excl = woff + incl - s;
        if (b0 < P) { hbase[b0] = excl;      cur[b0] = excl; }
        if (b1 < P) { hbase[b1] = excl + t0; cur[b1] = excl + t0; }
        if (t == 255) sTotal = excl + s;
        __syncthreads();

        // reload chunk c (src+dst) and place bucket-major into LDS
#pragma unroll
        for (int r = 0; r < 4; r++) {
            int e = base + c * 4096 + r * 1024 + t * 4;
            int4 S4, D4;
            if (e + 3 < E) {
                S4 = *(const int4*)(src + e);
                D4 = *(const int4*)(dst + e);
            } else {
                int s0[4], d0[4];
                for (int j = 0; j < 4; j++) {
                    int ee = e + j;
                    s0[j] = (ee < E) ? src[ee] : -1;
                    d0[j] = (ee < E) ? dst[ee] : -1;
                }
                S4 = make_int4(s0[0], s0[1], s0[2], s0[3]);
                D4 = make_int4(d0[0], d0[1], d0[2], d0[3]);
            }
            int ss[4] = { S4.x, S4.y, S4.z, S4.w };
            int dd[4] = { D4.x, D4.y, D4.z, D4.w };
#pragma unroll
            for (int j = 0; j < 4; j++) {
                int d = dd[j];
                if (d >= 0) {
                    int bk = d >> PSHIFT;
                    int pos = atomicAdd(&cur[bk], 1);
                    sortedv[pos] = ((unsigned)(d & (NPB - 1)) << 17) | (unsigned)ss[j];
                    bktid[pos]   = (u16)bk;
                }
            }
        }
        __syncthreads();

        int total = sTotal;
        for (int i = t; i < total; i += 256) {
            int bk = bktid[i];
            int addr = run[bk] + (i - hbase[bk]);
            if (addr < (bk + 1) * SLOTS)     // overflow guard (statistically unreachable)
                staged[addr] = sortedv[i];
        }
        __syncthreads();

        if (c < 3) {   // advance running cursor (owner thread; next read is 2+ barriers away)
            if (b0 < P && t0) run[b0] += t0;
            if (b1 < P && t1) run[b1] += t1;
        }
    }
}

// ---------------- phase 2: parallel scan over P bucket counts ----------------
__global__ void scan_buckets(const int* __restrict__ gcur, int* __restrict__ colbase,
                             int* __restrict__ rowptr, int P, int N) {
    __shared__ int wsums[4];
    int t = threadIdx.x, wid = t >> 6, lane = t & 63;
    int b0 = 2 * t, b1 = 2 * t + 1;
    int c0 = 0, c1 = 0;
    if (b0 < P) { c0 = gcur[b0 * GS] - b0 * SLOTS; if (c0 > SLOTS) c0 = SLOTS; }
    if (b1 < P) { c1 = gcur[b1 * GS] - b1 * SLOTS; if (c1 > SLOTS) c1 = SLOTS; }
    int s = c0 + c1;
    int incl = s;
#pragma unroll
    for (int off = 1; off < 64; off <<= 1) {
        int u = __shfl_up(incl, off, 64);
        if (lane >= off) incl += u;
    }
    if (lane == 63) wsums[wid] = incl;
    __syncthreads();
    int woff = 0;
#pragma unroll
    for (int w = 0; w < 4; w++) if (w < wid) woff += wsums[w];
    int excl = woff + incl - s;
    if (b0 < P) colbase[b0] = excl;
    if (b1 < P) colbase[b1] = excl + c0;
    if (t == 255) {
        colbase[P] = excl + s;
        rowptr[N]  = excl + s;
    }
}

// ---------------- phase 3: per-bucket counting sort ----------------
__global__ void sort_bucket(const unsigned* __restrict__ staged, const int* __restrict__ gcur,
                            const int* __restrict__ colbase,
                            int* __restrict__ rowptr, int* __restrict__ col, int N) {
    __shared__ int cnt[NBINS];
    __shared__ int wsum[4];
    __shared__ int sorted[SLOTS];
    int b = blockIdx.x;
    int t = threadIdx.x;
    int lane = t & 63, wid = t >> 6;
    int sBeg = b * SLOTS;
    int sEnd = gcur[b * GS]; if (sEnd > sBeg + SLOTS) sEnd = sBeg + SLOTS;
    int total = sEnd - sBeg;
    int colStart = colbase[b];
    int nodeBase = b << PSHIFT;

    for (int i = t; i < NBINS; i += 256) cnt[i] = 0;
    __syncthreads();
    for (int i = sBeg + t; i < sEnd; i += 256) {
        unsigned w = staged[i];
        int key = (int)((w >> 17) << SBITS) | (int)((w & 0x1FFFFu) >> 14);
        atomicAdd(&cnt[key], 1);
    }
    __syncthreads();

    int loc[SBINS]; int tot = 0;
#pragma unroll
    for (int k = 0; k < SBINS; k++) { loc[k] = tot; tot += cnt[(t << SBITS) + k]; }
    int incl = tot;
#pragma unroll
    for (int off = 1; off < 64; off <<= 1) {
        int u = __shfl_up(incl, off, 64);
        if (lane >= off) incl += u;
    }
    if (lane == 63) wsum[wid] = incl;
    __syncthreads();
    int woff = 0;
#pragma unroll
    for (int w = 0; w < 4; w++) if (w < wid) woff += wsum[w];
    int excl = woff + incl - tot;
    int node = nodeBase + t;
    if (node < N) rowptr[node] = colStart + excl;
#pragma unroll
    for (int k = 0; k < SBINS; k++) cnt[(t << SBITS) + k] = excl + loc[k];
    __syncthreads();

    for (int i = sBeg + t; i < sEnd; i += 256) {
        unsigned w = staged[i];
        int key = (int)((w >> 17) << SBITS) | (int)((w & 0x1FFFFu) >> 14);
        int pos = atomicAdd(&cnt[key], 1);
        sorted[pos] = (int)(w & 0x1FFFFu);
    }
    __syncthreads();
    for (int i = t; i < total; i += 256)
        col[colStart + i] = sorted[i];
}

// ---------------- layer 0 fused: gather(d=1) + MLP -> fp8 out ----------------
__global__ void mlp0_fused(const int* __restrict__ rowptr, const int* __restrict__ col,
                           const float* __restrict__ x0,
                           const float* __restrict__ W1, const float* __restrict__ b1,
                           const float* __restrict__ W2, const float* __restrict__ b2,
                           u8* __restrict__ out, int n) {
    __shared__ float sW1[HID], sb1[HID], sW2[HID * HID], sb2[HID];
    __shared__ int colbuf[COLBUF0];
    int t = threadIdx.x;
    if (t < HID) { sW1[t] = W1[t]; sb1[t] = b1[t]; sb2[t] = b2[t]; }
    for (int i = t; i < HID * HID; i += blockDim.x) sW2[i] = W2[i];

    int firstNode = blockIdx.x * 64;
    int lastNode  = firstNode + 64; if (lastNode > n) lastNode = n;
    int blockStart = (firstNode < n) ? rowptr[firstNode] : 0;
    int blockEnd   = (firstNode < n) ? rowptr[lastNode] : 0;
    int stagedCnt = blockEnd - blockStart; if (stagedCnt > COLBUF0) stagedCnt = COLBUF0;
    for (int i = t; i < stagedCnt; i += 256) colbuf[i] = col[blockStart + i];
    __syncthreads();

    int node = firstNode + (t >> 2);
    int q    = t & 3;
    int lane = t & 63;
    int base = lane & ~3;
    bool active = node < n;

    float s = 0.f;
    if (active) {
        int beg = rowptr[node], end = rowptr[node + 1];
        int jSplit = blockStart + stagedCnt; if (jSplit > end) jSplit = end;
        int j = beg + q;
        for (; j + 12 < jSplit; j += 16) {
            int c0 = colbuf[j - blockStart];
            int c1 = colbuf[j + 4 - blockStart];
            int c2 = colbuf[j + 8 - blockStart];
            int c3 = colbuf[j + 12 - blockStart];
            s += x0[c0]; s += x0[c1]; s += x0[c2]; s += x0[c3];
        }
        for (; j < jSplit; j += 4) s += x0[colbuf[j - blockStart]];
        for (; j < end; j += 4) s += x0[col[j]];
    }
    s += __shfl_xor(s, 1, 64);
    s += __shfl_xor(s, 2, 64);
    float v = active ? (x0[node] + s) : 0.f;

    float h[8];
#pragma unroll
    for (int i = 0; i < 8; i++) h[i] = fmaxf(fmaf(v, sW1[q * 8 + i], sb1[q * 8 + i]), 0.f);
    float o[8];
#pragma unroll
    for (int i = 0; i < 8; i++) o[i] = sb2[q * 8 + i];
#pragma unroll
    for (int k = 0; k < HID; k++) {
        float hk = __shfl(h[k & 7], base | (k >> 3), 64);
#pragma unroll
        for (int i = 0; i < 8; i++) o[i] = fmaf(hk, sW2[k * HID + q * 8 + i], o[i]);
    }
    if (active) {
        unsigned w0 = f2e4(fmaxf(o[0], 0.f)) | (f2e4(fmaxf(o[1], 0.f)) << 8)
                    | (f2e4(fmaxf(o[2], 0.f)) << 16) | (f2e4(fmaxf(o[3], 0.f)) << 24);
        unsigned w1 = f2e4(fmaxf(o[4], 0.f)) | (f2e4(fmaxf(o[5], 0.f)) << 8)
                    | (f2e4(fmaxf(o[6], 0.f)) << 16) | (f2e4(fmaxf(o[7], 0.f)) << 24);
        uint2 pk = make_uint2(w0, w1);
        *(uint2*)(out + ((size_t)node << 5) + (q << 3)) = pk;
    }
}

// ---------------- hidden layer fused: fp8 gather + MLP, 8 lanes/node, 32 nodes/block ----
template <bool REDUCE>
__global__ void mlp_fused(const int* __restrict__ rowptr, const int* __restrict__ col,
                          const u8* __restrict__ xin,
                          const float* __restrict__ W1, const float* __restrict__ b1,
                          const float* __restrict__ W2, const float* __restrict__ b2,
                          u8* __restrict__ xout, float* __restrict__ hsum, int n) {
    __shared__ float sW1[HID * HID], sb1[HID], sW2[HID * HID], sb2[HID];
    __shared__ int colbuf[COLBUF];
    __shared__ float red[4][HID];
    int t = threadIdx.x;
    for (int i = t; i < HID * HID; i += blockDim.x) { sW1[i] = W1[i]; sW2[i] = W2[i]; }
    if (t < HID) { sb1[t] = b1[t]; sb2[t] = b2[t]; }

    int firstNode = blockIdx.x * 32;
    int lastNode  = firstNode + 32; if (lastNode > n) lastNode = n;
    int blockStart = (firstNode < n) ? rowptr[firstNode] : 0;
    int blockEnd   = (firstNode < n) ? rowptr[lastNode] : 0;
    int stagedCnt = blockEnd - blockStart; if (stagedCnt > COLBUF) stagedCnt = COLBUF;
    for (int i = t; i < stagedCnt; i += 256) colbuf[i] = col[blockStart + i];
    __syncthreads();

    int node = firstNode + (t >> 3);
    int q    = t & 7;            // lane owns features [q*4, q*4+4)
    int lane = t & 63;
    int base = lane & ~7;
    bool active = node < n;

    float va[4];
#pragma unroll
    for (int i = 0; i < 4; i++) va[i] = 0.f;
    if (active) {
        int beg = rowptr[node], end = rowptr[node + 1];
        const u8* xq = xin + (q << 2);
        float a0[4], a1[4], a2[4], a3[4];
#pragma unroll
        for (int i = 0; i < 4; i++) a0[i] = a1[i] = a2[i] = a3[i] = 0.f;
        {   // self term (eps = 0)
            unsigned w = *(const unsigned*)(xq + ((size_t)node << 5));
            acc_e4(a0, w);
        }
        int jSplit = blockStart + stagedCnt; if (jSplit > end) jSplit = end;
        int j = beg;
        for (; j + 8 <= jSplit; j += 8) {
            int lj = j - blockStart;
            int c0 = colbuf[lj+0], c1 = colbuf[lj+1], c2 = colbuf[lj+2], c3 = colbuf[lj+3];
            int c4 = colbuf[lj+4], c5 = colbuf[lj+5], c6 = colbuf[lj+6], c7 = colbuf[lj+7];
            unsigned w0 = *(const unsigned*)(xq + ((size_t)c0 << 5));
            unsigned w1 = *(const unsigned*)(xq + ((size_t)c1 << 5));
            unsigned w2 = *(const unsigned*)(xq + ((size_t)c2 << 5));
            unsigned w3 = *(const unsigned*)(xq + ((size_t)c3 << 5));
            unsigned w4 = *(const unsigned*)(xq + ((size_t)c4 << 5));
            unsigned w5 = *(const unsigned*)(xq + ((size_t)c5 << 5));
            unsigned w6 = *(const unsigned*)(xq + ((size_t)c6 << 5));
            unsigned w7 = *(const unsigned*)(xq + ((size_t)c7 << 5));
            acc_e4(a0, w0); acc_e4(a1, w1); acc_e4(a2, w2); acc_e4(a3, w3);
            acc_e4(a0, w4); acc_e4(a1, w5); acc_e4(a2, w6); acc_e4(a3, w7);
        }
        for (; j < jSplit; j++) {
            unsigned w = *(const unsigned*)(xq + ((size_t)colbuf[j - blockStart] << 5));
            acc_e4(a0, w);
        }
        for (; j < end; j++) {   // colbuf overflow fallback (statistically unreachable)
            unsigned w = *(const unsigned*)(xq + ((size_t)col[j] << 5));
            acc_e4(a0, w);
        }
#pragma unroll
        for (int i = 0; i < 4; i++) va[i] = (a0[i] + a1[i]) + (a2[i] + a3[i]);
    }

    float h[4];
#pragma unroll
    for (int i = 0; i < 4; i++) h[i] = sb1[q * 4 + i];
#pragma unroll
    for (int k = 0; k < HID; k++) {
        float vk = __shfl(va[k & 3], base | (k >> 2), 64);
#pragma unroll
        for (int i = 0; i < 4; i++) h[i] = fmaf(vk, sW1[k * HID + q * 4 + i], h[i]);
    }
#pragma unroll
    for (int i = 0; i < 4; i++) h[i] = fmaxf(h[i], 0.f);

    float o[4];
#pragma unroll
    for (int i = 0; i < 4; i++) o[i] = sb2[q * 4 + i];
#pragma unroll
    for (int k = 0; k < HID; k++) {
        float hk = __shfl(h[k & 3], base | (k >> 2), 64);
#pragma unroll
        for (int i = 0; i < 4; i++) o[i] = fmaf(hk, sW2[k * HID + q * 4 + i], o[i]);
    }
#pragma unroll
    for (int i = 0; i < 4; i++) o[i] = fmaxf(o[i], 0.f);

    if (REDUCE) {
        if (!active) {
#pragma unroll
            for (int i = 0; i < 4; i++) o[i] = 0.f;
        }
#pragma unroll
        for (int i = 0; i < 4; i++) {   // sum the 8 nodes of this wave (lane bits 3..5)
            float v = o[i];
            v += __shfl_xor(v, 8, 64);
            v += __shfl_xor(v, 16, 64);
            v += __shfl_xor(v, 32, 64);
            o[i] = v;
        }
        int wid = t >> 6;
        if (lane < 8) {
#pragma unroll
            for (int i = 0; i < 4; i++) red[wid][lane * 4 + i] = o[i];
        }
        __syncthreads();
        if (t < HID) {
            float s = red[0][t] + red[1][t] + red[2][t] + red[3][t];
            atomicAdd(&hsum[(blockIdx.x & (HS_ROWS - 1)) * (2 * HID) + t], s);
        }
    } else if (active) {
        unsigned pw = f2e4(o[0]) | (f2e4(o[1]) << 8) | (f2e4(o[2]) << 16) | (f2e4(o[3]) << 24);
        *(unsigned*)(xout + ((size_t)node << 5) + (q << 2)) = pw;
    }
}

// ---------------- head ----------------
__global__ void head_kernel(const float* __restrict__ hsumP,
                            const float* __restrict__ Wc1, const float* __restrict__ bc1,
                            const float* __restrict__ Wc2, const float* __restrict__ bc2,
                            float* __restrict__ out) {
    __shared__ float hs[2 * HID];
    int t = threadIdx.x;
    if (t < 2 * HID) {
        float s = 0.f;
        for (int r = 0; r < HS_ROWS; r++) s += hsumP[r * (2 * HID) + t];
        hs[t] = s;
    }
    __syncthreads();
    float val = 0.f;
    if (t < HID) {
        float acc = bc1[t];
        for (int i = 0; i < 2 * HID; i++) acc = fmaf(hs[i], Wc1[i * HID + t], acc);
        val = fmaxf(acc, 0.f) * Wc2[t];
    }
    for (int off = 32; off >= 1; off >>= 1) val += __shfl_xor(val, off, 64);
    if (t == 0) out[0] = 1.f / (1.f + expf(-(val + bc2[0])));
}

extern "C" void kernel_launch(void* const* d_in, const int* in_sizes, int n_in,
                              void* d_out, int out_size, void* d_ws, size_t ws_size,
                              hipStream_t stream) {
    const float* xg[2] = { (const float*)d_in[0], (const float*)d_in[2] };
    const int*   eg[2] = { (const int*)d_in[1],   (const int*)d_in[3] };
    const float* W1[3] = { (const float*)d_in[4], (const float*)d_in[8],  (const float*)d_in[12] };
    const float* b1[3] = { (const float*)d_in[5], (const float*)d_in[9],  (const float*)d_in[13] };
    const float* W2[3] = { (const float*)d_in[6], (const float*)d_in[10], (const float*)d_in[14] };
    const float* b2[3] = { (const float*)d_in[7], (const float*)d_in[11], (const float*)d_in[15] };
    const float* Wc1 = (const float*)d_in[16];
    const float* bc1 = (const float*)d_in[17];
    const float* Wc2 = (const float*)d_in[18];
    const float* bc2 = (const float*)d_in[19];

    const int N = in_sizes[0];
    const int E = in_sizes[1] / 2;
    const int P = (N + NPB - 1) >> PSHIFT;   // 391 for N=100000

    // workspace layout (~60 MB)
    u8*       B0      = (u8*)d_ws;                        // N*32 bytes fp8 (3.2 MB)
    u8*       B1      = B0 + (size_t)N * 32;              // N*32 bytes fp8
    float*    hsumP   = (float*)(B1 + (size_t)N * 32);    // HS_ROWS * 2*HID partials
    int*      rowptr  = (int*)(hsumP + HS_ROWS * 2 * HID); // N+1
    int*      col     = rowptr + (N + 1);                 // E
    int*      colbase = col + (size_t)E;                  // P+1
    int*      gcur    = colbase + (P + 1);                // P*GS (cacheline-padded)
    unsigned* staged  = (unsigned*)(gcur + (size_t)P * GS); // P*SLOTS (27.2 MB)

    const int TB = 256;
    dim3 blk(TB);
    int gE16k = (E + EPB - 1) / EPB;         // 391 partition blocks (all resident)
    int gN64 = (N + 63) / 64;                // mlp0: 4 lanes/node, 64 nodes/block
    int gN8  = (N + 31) / 32;                // mlp:  8 lanes/node, 32 nodes/block
    int gP   = (P + TB - 1) / TB;

    zero_kernel<<<(HS_ROWS * 2 * HID + 255) / 256, 256, 0, stream>>>(hsumP, HS_ROWS * 2 * HID);

    for (int g = 0; g < 2; g++) {
        const float* x0  = xg[g];
        const int*   src = eg[g];
        const int*   dst = src + E;

        // ---- adjacency build: partition -> scan -> per-bucket sort ----
        init_gcur<<<gP, blk, 0, stream>>>(gcur, P);
        partition_edges<<<gE16k, blk, 0, stream>>>(src, dst, gcur, staged, E, P);
        scan_buckets<<<1, blk, 0, stream>>>(gcur, colbase, rowptr, P, N);
        sort_bucket<<<P, blk, 0, stream>>>(staged, gcur, colbase, rowptr, col, N);

        // ---- layer 0 (d_in = 1), fp32 gather -> fp8 features ----
        mlp0_fused<<<gN64, blk, 0, stream>>>(rowptr, col, x0, W1[0], b1[0], W2[0], b2[0], B0, N);

        // ---- layer 1: fp8 gather+MLP  B0 -> B1 ----
        mlp_fused<false><<<gN8, blk, 0, stream>>>(rowptr, col, B0, W1[1], b1[1], W2[1], b2[1],
                                                  B1, nullptr, N);

        // ---- layer 2: fp8 gather+MLP + global add-pool ----
        mlp_fused<true><<<gN8, blk, 0, stream>>>(rowptr, col, B1, W1[2], b1[2], W2[2], b2[2],
                                                 nullptr, hsumP + g * HID, N);
    }

    head_kernel<<<1, 64, 0, stream>>>(hsumP, Wc1, bc1, Wc2, bc2, (float*)d_out);
}

// Round 9
// 571.548 us; speedup vs baseline: 1.0263x; 1.0263x over previous
//
#include <hip/hip_runtime.h>
#include <hip/hip_bf16.h>
#include <math.h>
#include <string.h>

#define HID 32
#define PSHIFT 8                 // dst bucket = dst >> 8 (256 nodes/bucket)
#define NPB (1 << PSHIFT)
#define MAXP 512                 // partition scan width (supports N <= 131072)
#define SLOTS 17408              // per-bucket staging; mean 16384, +8 sigma (guarded)
#define SBITS 3                  // src octile bits: bin = src >> 14
#define SBINS (1 << SBITS)
#define NBINS (NPB * SBINS)      // 2048 counting-sort bins
#define GS 32                    // gcur stride in ints: 1 counter per 128B cacheline
#define HS_ROWS 32               // hsum partial rows (spread atomic contention)
#define COLBUF 3072              // mlp_fused col slice; 32 nodes, mean 2048 (guarded)
#define COLBUF0 6144             // mlp0 col slice; 64 nodes, mean 4096 (guarded)
typedef unsigned short u16;
typedef unsigned char u8;
typedef float f32x2 __attribute__((ext_vector_type(2)));

// ---------- fp8 e4m3 helpers (OCP; non-negative activations) ----------
// software fallback decode: (b&0x7f)<<20 * 2^120 reproduces 2^(e-7)*(1+m/8)
__device__ inline float e42f_sw(unsigned b) {
    unsigned u = (b & 0x7fu) << 20;
    float f; memcpy(&f, &u, 4);
    return f * 0x1p120f;
}
__device__ inline unsigned f2e4_sw(float f) {
    f = fminf(f, 448.f);
    float y = f * 0x1p-120f;
    unsigned r; memcpy(&r, &y, 4);
    r = r + 0x7FFFFu + ((r >> 20) & 1u);
    return (r >> 20) & 0x7fu;
}
// accumulate 4 e4m3 (one u32) into a[0..3] — HW cvt when available (R9: VALU cut)
__device__ inline void acc_e4(float* a, unsigned w) {
#if __has_builtin(__builtin_amdgcn_cvt_pk_f32_fp8)
    f32x2 lo = __builtin_amdgcn_cvt_pk_f32_fp8(w, false);   // bytes 0,1
    f32x2 hi = __builtin_amdgcn_cvt_pk_f32_fp8(w, true);    // bytes 2,3
    a[0] += lo.x; a[1] += lo.y; a[2] += hi.x; a[3] += hi.y;
#else
    a[0] += e42f_sw(w);
    a[1] += e42f_sw(w >> 8);
    a[2] += e42f_sw(w >> 16);
    a[3] += e42f_sw(w >> 24);
#endif
}
// pack 4 non-negative floats -> 4 e4m3 bytes
__device__ inline unsigned pack_e4(float o0, float o1, float o2, float o3) {
#if __has_builtin(__builtin_amdgcn_cvt_pk_fp8_f32)
    unsigned pw = (unsigned)__builtin_amdgcn_cvt_pk_fp8_f32(
        fminf(o0, 448.f), fminf(o1, 448.f), 0, false);
    pw = (unsigned)__builtin_amdgcn_cvt_pk_fp8_f32(
        fminf(o2, 448.f), fminf(o3, 448.f), pw, true);
    return pw;
#else
    return f2e4_sw(o0) | (f2e4_sw(o1) << 8) | (f2e4_sw(o2) << 16) | (f2e4_sw(o3) << 24);
#endif
}

// ---------------- zero / init ----------------
__global__ void zero_kernel(float* __restrict__ p, int n) {
    int i = blockIdx.x * blockDim.x + threadIdx.x;
    if (i < n) p[i] = 0.f;
}
__global__ void init_gcur(int* __restrict__ gcur, int P) {
    int b = blockIdx.x * blockDim.x + threadIdx.x;
    if (b < P) gcur[b * GS] = b * SLOTS;
}

// ---------------- phase 1: partition (R7 version — proven fastest) ----------------
// R8 evidence: 4x fewer gcur atomics did NOT help (per-CU-pipe-bound, not atomics).
__global__ void partition_edges(const int* __restrict__ src, const int* __restrict__ dst,
                                int* __restrict__ gcur, unsigned* __restrict__ staged,
                                int E, int P) {
    __shared__ int h[4][MAXP];
    __shared__ int hbase[MAXP];
    __shared__ int cur[MAXP];
    __shared__ int gbase[MAXP];
    __shared__ unsigned sortedv[4096];
    __shared__ u16 bktid[4096];
    __shared__ int wsums[4];
    __shared__ int sTotal;
    int t = threadIdx.x, wid = t >> 6, lane = t & 63;
    for (int i = t; i < 4 * MAXP; i += 256) (&h[0][0])[i] = 0;
    __syncthreads();

    int base = blockIdx.x * 4096;
    int4 S[4], D[4];
#pragma unroll
    for (int r = 0; r < 4; r++) {
        int e = base + r * 1024 + t * 4;
        if (e + 3 < E) {
            S[r] = *(const int4*)(src + e);
            D[r] = *(const int4*)(dst + e);
        } else {
            int s0[4], d0[4];
            for (int j = 0; j < 4; j++) {
                int ee = e + j;
                s0[j] = (ee < E) ? src[ee] : -1;
                d0[j] = (ee < E) ? dst[ee] : -1;
            }
            S[r] = make_int4(s0[0], s0[1], s0[2], s0[3]);
            D[r] = make_int4(d0[0], d0[1], d0[2], d0[3]);
        }
        if (D[r].x >= 0) atomicAdd(&h[wid][D[r].x >> PSHIFT], 1);
        if (D[r].y >= 0) atomicAdd(&h[wid][D[r].y >> PSHIFT], 1);
        if (D[r].z >= 0) atomicAdd(&h[wid][D[r].z >> PSHIFT], 1);
        if (D[r].w >= 0) atomicAdd(&h[wid][D[r].w >> PSHIFT], 1);
    }
    __syncthreads();

    int b0 = 2 * t, b1 = 2 * t + 1;
    int t0 = (b0 < P) ? (h[0][b0] + h[1][b0] + h[2][b0] + h[3][b0]) : 0;
    int t1 = (b1 < P) ? (h[0][b1] + h[1][b1] + h[2][b1] + h[3][b1]) : 0;
    int s = t0 + t1;
    int incl = s;
#pragma unroll
    for (int off = 1; off < 64; off <<= 1) {
        int u = __shfl_up(incl, off, 64);
        if (lane >= off) incl += u;
    }
    if (lane == 63) wsums[wid] = incl;
    __syncthreads();
    int woff = 0;
#pragma unroll
    for (int w = 0; w < 4; w++) if (w < wid) woff += wsums[w];
    int excl = woff + incl - s;
    if (b0 < P) { hbase[b0] = excl;      cur[b0] = excl; }
    if (b1 < P) { hbase[b1] = excl + t0; cur[b1] = excl + t0; }
    if (b0 < P && t0) gbase[b0] = atomicAdd(&gcur[b0 * GS], t0);
    if (b1 < P && t1) gbase[b1] = atomicAdd(&gcur[b1 * GS], t1);
    if (t == 255) sTotal = excl + s;
    __syncthreads();

#pragma unroll
    for (int r = 0; r < 4; r++) {
        int ss[4] = { S[r].x, S[r].y, S[r].z, S[r].w };
        int dd[4] = { D[r].x, D[r].y, D[r].z, D[r].w };
#pragma unroll
        for (int j = 0; j < 4; j++) {
            int d = dd[j];
            if (d >= 0) {
                int bk = d >> PSHIFT;
                int pos = atomicAdd(&cur[bk], 1);
                sortedv[pos] = ((unsigned)(d & (NPB - 1)) << 17) | (unsigned)ss[j];
                bktid[pos]   = (u16)bk;
            }
        }
    }
    __syncthreads();

    int total = sTotal;
    for (int i = t; i < total; i += 256) {
        int bk = bktid[i];
        int addr = gbase[bk] + (i - hbase[bk]);
        if (addr < (bk + 1) * SLOTS)
            staged[addr] = sortedv[i];
    }
}

// ---------------- phase 2: parallel scan over P bucket counts ----------------
__global__ void scan_buckets(const int* __restrict__ gcur, int* __restrict__ colbase,
                             int* __restrict__ rowptr, int P, int N) {
    __shared__ int wsums[4];
    int t = threadIdx.x, wid = t >> 6, lane = t & 63;
    int b0 = 2 * t, b1 = 2 * t + 1;
    int c0 = 0, c1 = 0;
    if (b0 < P) { c0 = gcur[b0 * GS] - b0 * SLOTS; if (c0 > SLOTS) c0 = SLOTS; }
    if (b1 < P) { c1 = gcur[b1 * GS] - b1 * SLOTS; if (c1 > SLOTS) c1 = SLOTS; }
    int s = c0 + c1;
    int incl = s;
#pragma unroll
    for (int off = 1; off < 64; off <<= 1) {
        int u = __shfl_up(incl, off, 64);
        if (lane >= off) incl += u;
    }
    if (lane == 63) wsums[wid] = incl;
    __syncthreads();
    int woff = 0;
#pragma unroll
    for (int w = 0; w < 4; w++) if (w < wid) woff += wsums[w];
    int excl = woff + incl - s;
    if (b0 < P) colbase[b0] = excl;
    if (b1 < P) colbase[b1] = excl + c0;
    if (t == 255) {
        colbase[P] = excl + s;
        rowptr[N]  = excl + s;
    }
}

// ---------------- phase 3: per-bucket counting sort ----------------
__global__ void sort_bucket(const unsigned* __restrict__ staged, const int* __restrict__ gcur,
                            const int* __restrict__ colbase,
                            int* __restrict__ rowptr, int* __restrict__ col, int N) {
    __shared__ int cnt[NBINS];
    __shared__ int wsum[4];
    __shared__ int sorted[SLOTS];
    int b = blockIdx.x;
    int t = threadIdx.x;
    int lane = t & 63, wid = t >> 6;
    int sBeg = b * SLOTS;
    int sEnd = gcur[b * GS]; if (sEnd > sBeg + SLOTS) sEnd = sBeg + SLOTS;
    int total = sEnd - sBeg;
    int colStart = colbase[b];
    int nodeBase = b << PSHIFT;

    for (int i = t; i < NBINS; i += 256) cnt[i] = 0;
    __syncthreads();
    for (int i = sBeg + t; i < sEnd; i += 256) {
        unsigned w = staged[i];
        int key = (int)((w >> 17) << SBITS) | (int)((w & 0x1FFFFu) >> 14);
        atomicAdd(&cnt[key], 1);
    }
    __syncthreads();

    int loc[SBINS]; int tot = 0;
#pragma unroll
    for (int k = 0; k < SBINS; k++) { loc[k] = tot; tot += cnt[(t << SBITS) + k]; }
    int incl = tot;
#pragma unroll
    for (int off = 1; off < 64; off <<= 1) {
        int u = __shfl_up(incl, off, 64);
        if (lane >= off) incl += u;
    }
    if (lane == 63) wsum[wid] = incl;
    __syncthreads();
    int woff = 0;
#pragma unroll
    for (int w = 0; w < 4; w++) if (w < wid) woff += wsum[w];
    int excl = woff + incl - tot;
    int node = nodeBase + t;
    if (node < N) rowptr[node] = colStart + excl;
#pragma unroll
    for (int k = 0; k < SBINS; k++) cnt[(t << SBITS) + k] = excl + loc[k];
    __syncthreads();

    for (int i = sBeg + t; i < sEnd; i += 256) {
        unsigned w = staged[i];
        int key = (int)((w >> 17) << SBITS) | (int)((w & 0x1FFFFu) >> 14);
        int pos = atomicAdd(&cnt[key], 1);
        sorted[pos] = (int)(w & 0x1FFFFu);
    }
    __syncthreads();
    for (int i = t; i < total; i += 256)
        col[colStart + i] = sorted[i];
}

// ---------------- layer 0 fused: gather(d=1) + MLP -> fp8 out ----------------
__global__ void mlp0_fused(const int* __restrict__ rowptr, const int* __restrict__ col,
                           const float* __restrict__ x0,
                           const float* __restrict__ W1, const float* __restrict__ b1,
                           const float* __restrict__ W2, const float* __restrict__ b2,
                           u8* __restrict__ out, int n) {
    __shared__ float sW1[HID], sb1[HID], sW2[HID * HID], sb2[HID];
    __shared__ int colbuf[COLBUF0];
    int t = threadIdx.x;
    if (t < HID) { sW1[t] = W1[t]; sb1[t] = b1[t]; sb2[t] = b2[t]; }
    for (int i = t; i < HID * HID; i += blockDim.x) sW2[i] = W2[i];

    int firstNode = blockIdx.x * 64;
    int lastNode  = firstNode + 64; if (lastNode > n) lastNode = n;
    int blockStart = (firstNode < n) ? rowptr[firstNode] : 0;
    int blockEnd   = (firstNode < n) ? rowptr[lastNode] : 0;
    int stagedCnt = blockEnd - blockStart; if (stagedCnt > COLBUF0) stagedCnt = COLBUF0;
    for (int i = t; i < stagedCnt; i += 256) colbuf[i] = col[blockStart + i];
    __syncthreads();

    int node = firstNode + (t >> 2);
    int q    = t & 3;
    int lane = t & 63;
    int base = lane & ~3;
    bool active = node < n;

    float s = 0.f;
    if (active) {
        int beg = rowptr[node], end = rowptr[node + 1];
        int jSplit = blockStart + stagedCnt; if (jSplit > end) jSplit = end;
        int j = beg + q;
        for (; j + 12 < jSplit; j += 16) {
            int c0 = colbuf[j - blockStart];
            int c1 = colbuf[j + 4 - blockStart];
            int c2 = colbuf[j + 8 - blockStart];
            int c3 = colbuf[j + 12 - blockStart];
            s += x0[c0]; s += x0[c1]; s += x0[c2]; s += x0[c3];
        }
        for (; j < jSplit; j += 4) s += x0[colbuf[j - blockStart]];
        for (; j < end; j += 4) s += x0[col[j]];
    }
    s += __shfl_xor(s, 1, 64);
    s += __shfl_xor(s, 2, 64);
    float v = active ? (x0[node] + s) : 0.f;

    float h[8];
#pragma unroll
    for (int i = 0; i < 8; i++) h[i] = fmaxf(fmaf(v, sW1[q * 8 + i], sb1[q * 8 + i]), 0.f);
    float o[8];
#pragma unroll
    for (int i = 0; i < 8; i++) o[i] = sb2[q * 8 + i];
#pragma unroll
    for (int k = 0; k < HID; k++) {
        float hk = __shfl(h[k & 7], base | (k >> 3), 64);
#pragma unroll
        for (int i = 0; i < 8; i++) o[i] = fmaf(hk, sW2[k * HID + q * 8 + i], o[i]);
    }
    if (active) {
        unsigned w0 = pack_e4(fmaxf(o[0], 0.f), fmaxf(o[1], 0.f),
                              fmaxf(o[2], 0.f), fmaxf(o[3], 0.f));
        unsigned w1 = pack_e4(fmaxf(o[4], 0.f), fmaxf(o[5], 0.f),
                              fmaxf(o[6], 0.f), fmaxf(o[7], 0.f));
        uint2 pk = make_uint2(w0, w1);
        *(uint2*)(out + ((size_t)node << 5) + (q << 3)) = pk;
    }
}

// ---------------- hidden layer fused: fp8 gather + MLP, 8 lanes/node, 32 nodes/block ----
// fp8 table 3.2MB < 4MB/XCD L2 (R7 win). HW v_cvt_pk_f32_fp8 decode (R9).
template <bool REDUCE>
__global__ void mlp_fused(const int* __restrict__ rowptr, const int* __restrict__ col,
                          const u8* __restrict__ xin,
                          const float* __restrict__ W1, const float* __restrict__ b1,
                          const float* __restrict__ W2, const float* __restrict__ b2,
                          u8* __restrict__ xout, float* __restrict__ hsum, int n) {
    __shared__ float sW1[HID * HID], sb1[HID], sW2[HID * HID], sb2[HID];
    __shared__ int colbuf[COLBUF];
    __shared__ float red[4][HID];
    int t = threadIdx.x;
    for (int i = t; i < HID * HID; i += blockDim.x) { sW1[i] = W1[i]; sW2[i] = W2[i]; }
    if (t < HID) { sb1[t] = b1[t]; sb2[t] = b2[t]; }

    int firstNode = blockIdx.x * 32;
    int lastNode  = firstNode + 32; if (lastNode > n) lastNode = n;
    int blockStart = (firstNode < n) ? rowptr[firstNode] : 0;
    int blockEnd   = (firstNode < n) ? rowptr[lastNode] : 0;
    int stagedCnt = blockEnd - blockStart; if (stagedCnt > COLBUF) stagedCnt = COLBUF;
    for (int i = t; i < stagedCnt; i += 256) colbuf[i] = col[blockStart + i];
    __syncthreads();

    int node = firstNode + (t >> 3);
    int q    = t & 7;            // lane owns features [q*4, q*4+4)
    int lane = t & 63;
    int base = lane & ~7;
    bool active = node < n;

    float va[4];
#pragma unroll
    for (int i = 0; i < 4; i++) va[i] = 0.f;
    if (active) {
        int beg = rowptr[node], end = rowptr[node + 1];
        const u8* xq = xin + (q << 2);
        float a0[4], a1[4], a2[4], a3[4];
#pragma unroll
        for (int i = 0; i < 4; i++) a0[i] = a1[i] = a2[i] = a3[i] = 0.f;
        {   // self term (eps = 0)
            unsigned w = *(const unsigned*)(xq + ((size_t)node << 5));
            acc_e4(a0, w);
        }
        int jSplit = blockStart + stagedCnt; if (jSplit > end) jSplit = end;
        int j = beg;
        for (; j + 8 <= jSplit; j += 8) {
            int lj = j - blockStart;
            int c0 = colbuf[lj+0], c1 = colbuf[lj+1], c2 = colbuf[lj+2], c3 = colbuf[lj+3];
            int c4 = colbuf[lj+4], c5 = colbuf[lj+5], c6 = colbuf[lj+6], c7 = colbuf[lj+7];
            unsigned w0 = *(const unsigned*)(xq + ((size_t)c0 << 5));
            unsigned w1 = *(const unsigned*)(xq + ((size_t)c1 << 5));
            unsigned w2 = *(const unsigned*)(xq + ((size_t)c2 << 5));
            unsigned w3 = *(const unsigned*)(xq + ((size_t)c3 << 5));
            unsigned w4 = *(const unsigned*)(xq + ((size_t)c4 << 5));
            unsigned w5 = *(const unsigned*)(xq + ((size_t)c5 << 5));
            unsigned w6 = *(const unsigned*)(xq + ((size_t)c6 << 5));
            unsigned w7 = *(const unsigned*)(xq + ((size_t)c7 << 5));
            acc_e4(a0, w0); acc_e4(a1, w1); acc_e4(a2, w2); acc_e4(a3, w3);
            acc_e4(a0, w4); acc_e4(a1, w5); acc_e4(a2, w6); acc_e4(a3, w7);
        }
        for (; j < jSplit; j++) {
            unsigned w = *(const unsigned*)(xq + ((size_t)colbuf[j - blockStart] << 5));
            acc_e4(a0, w);
        }
        for (; j < end; j++) {   // colbuf overflow fallback (statistically unreachable)
            unsigned w = *(const unsigned*)(xq + ((size_t)col[j] << 5));
            acc_e4(a0, w);
        }
#pragma unroll
        for (int i = 0; i < 4; i++) va[i] = (a0[i] + a1[i]) + (a2[i] + a3[i]);
    }

    float h[4];
#pragma unroll
    for (int i = 0; i < 4; i++) h[i] = sb1[q * 4 + i];
#pragma unroll
    for (int k = 0; k < HID; k++) {
        float vk = __shfl(va[k & 3], base | (k >> 2), 64);
#pragma unroll
        for (int i = 0; i < 4; i++) h[i] = fmaf(vk, sW1[k * HID + q * 4 + i], h[i]);
    }
#pragma unroll
    for (int i = 0; i < 4; i++) h[i] = fmaxf(h[i], 0.f);

    float o[4];
#pragma unroll
    for (int i = 0; i < 4; i++) o[i] = sb2[q * 4 + i];
#pragma unroll
    for (int k = 0; k < HID; k++) {
        float hk = __shfl(h[k & 3], base | (k >> 2), 64);
#pragma unroll
        for (int i = 0; i < 4; i++) o[i] = fmaf(hk, sW2[k * HID + q * 4 + i], o[i]);
    }
#pragma unroll
    for (int i = 0; i < 4; i++) o[i] = fmaxf(o[i], 0.f);

    if (REDUCE) {
        if (!active) {
#pragma unroll
            for (int i = 0; i < 4; i++) o[i] = 0.f;
        }
#pragma unroll
        for (int i = 0; i < 4; i++) {   // sum the 8 nodes of this wave (lane bits 3..5)
            float v = o[i];
            v += __shfl_xor(v, 8, 64);
            v += __shfl_xor(v, 16, 64);
            v += __shfl_xor(v, 32, 64);
            o[i] = v;
        }
        int wid = t >> 6;
        if (lane < 8) {
#pragma unroll
            for (int i = 0; i < 4; i++) red[wid][lane * 4 + i] = o[i];
        }
        __syncthreads();
        if (t < HID) {
            float s = red[0][t] + red[1][t] + red[2][t] + red[3][t];
            atomicAdd(&hsum[(blockIdx.x & (HS_ROWS - 1)) * (2 * HID) + t], s);
        }
    } else if (active) {
        unsigned pw = pack_e4(o[0], o[1], o[2], o[3]);
        *(unsigned*)(xout + ((size_t)node << 5) + (q << 2)) = pw;
    }
}

// ---------------- head ----------------
__global__ void head_kernel(const float* __restrict__ hsumP,
                            const float* __restrict__ Wc1, const float* __restrict__ bc1,
                            const float* __restrict__ Wc2, const float* __restrict__ bc2,
                            float* __restrict__ out) {
    __shared__ float hs[2 * HID];
    int t = threadIdx.x;
    if (t < 2 * HID) {
        float s = 0.f;
        for (int r = 0; r < HS_ROWS; r++) s += hsumP[r * (2 * HID) + t];
        hs[t] = s;
    }
    __syncthreads();
    float val = 0.f;
    if (t < HID) {
        float acc = bc1[t];
        for (int i = 0; i < 2 * HID; i++) acc = fmaf(hs[i], Wc1[i * HID + t], acc);
        val = fmaxf(acc, 0.f) * Wc2[t];
    }
    for (int off = 32; off >= 1; off >>= 1) val += __shfl_xor(val, off, 64);
    if (t == 0) out[0] = 1.f / (1.f + expf(-(val + bc2[0])));
}

extern "C" void kernel_launch(void* const* d_in, const int* in_sizes, int n_in,
                              void* d_out, int out_size, void* d_ws, size_t ws_size,
                              hipStream_t stream) {
    const float* xg[2] = { (const float*)d_in[0], (const float*)d_in[2] };
    const int*   eg[2] = { (const int*)d_in[1],   (const int*)d_in[3] };
    const float* W1[3] = { (const float*)d_in[4], (const float*)d_in[8],  (const float*)d_in[12] };
    const float* b1[3] = { (const float*)d_in[5], (const float*)d_in[9],  (const float*)d_in[13] };
    const float* W2[3] = { (const float*)d_in[6], (const float*)d_in[10], (const float*)d_in[14] };
    const float* b2[3] = { (const float*)d_in[7], (const float*)d_in[11], (const float*)d_in[15] };
    const float* Wc1 = (const float*)d_in[16];
    const float* bc1 = (const float*)d_in[17];
    const float* Wc2 = (const float*)d_in[18];
    const float* bc2 = (const float*)d_in[19];

    const int N = in_sizes[0];
    const int E = in_sizes[1] / 2;
    const int P = (N + NPB - 1) >> PSHIFT;   // 391 for N=100000

    // workspace layout (~60 MB)
    u8*       B0      = (u8*)d_ws;                        // N*32 bytes fp8 (3.2 MB)
    u8*       B1      = B0 + (size_t)N * 32;              // N*32 bytes fp8
    float*    hsumP   = (float*)(B1 + (size_t)N * 32);    // HS_ROWS * 2*HID partials
    int*      rowptr  = (int*)(hsumP + HS_ROWS * 2 * HID); // N+1
    int*      col     = rowptr + (N + 1);                 // E
    int*      colbase = col + (size_t)E;                  // P+1
    int*      gcur    = colbase + (P + 1);                // P*GS (cacheline-padded)
    unsigned* staged  = (unsigned*)(gcur + (size_t)P * GS); // P*SLOTS (27.2 MB)

    const int TB = 256;
    dim3 blk(TB);
    int gE4k = (E + 4095) / 4096;            // 1563 partition blocks (R7 geometry)
    int gN64 = (N + 63) / 64;                // mlp0: 4 lanes/node, 64 nodes/block
    int gN8  = (N + 31) / 32;                // mlp:  8 lanes/node, 32 nodes/block
    int gP   = (P + TB - 1) / TB;

    zero_kernel<<<(HS_ROWS * 2 * HID + 255) / 256, 256, 0, stream>>>(hsumP, HS_ROWS * 2 * HID);

    for (int g = 0; g < 2; g++) {
        const float* x0  = xg[g];
        const int*   src = eg[g];
        const int*   dst = src + E;

        // ---- adjacency build: partition -> scan -> per-bucket sort ----
        init_gcur<<<gP, blk, 0, stream>>>(gcur, P);
        partition_edges<<<gE4k, blk, 0, stream>>>(src, dst, gcur, staged, E, P);
        scan_buckets<<<1, blk, 0, stream>>>(gcur, colbase, rowptr, P, N);
        sort_bucket<<<P, blk, 0, stream>>>(staged, gcur, colbase, rowptr, col, N);

        // ---- layer 0 (d_in = 1), fp32 gather -> fp8 features ----
        mlp0_fused<<<gN64, blk, 0, stream>>>(rowptr, col, x0, W1[0], b1[0], W2[0], b2[0], B0, N);

        // ---- layer 1: fp8 gather+MLP  B0 -> B1 ----
        mlp_fused<false><<<gN8, blk, 0, stream>>>(rowptr, col, B0, W1[1], b1[1], W2[1], b2[1],
                                                  B1, nullptr, N);

        // ---- layer 2: fp8 gather+MLP + global add-pool ----
        mlp_fused<true><<<gN8, blk, 0, stream>>>(rowptr, col, B1, W1[2], b1[2], W2[2], b2[2],
                                                 nullptr, hsumP + g * HID, N);
    }

    head_kernel<<<1, 64, 0, stream>>>(hsumP, Wc1, bc1, Wc2, bc2, (float*)d_out);
}